// Round 1
// baseline (1565.050 us; speedup 1.0000x reference)
//
#include <hip/hip_runtime.h>
#include <cstdint>
#include <cstddef>

// ---------------------------------------------------------------------------
// EnrichAttention: B=32, L1=L2=512, H=A=256, 3H=768, 2H=512
// Round 0: correct fp32 baseline.
//   gemm_f32<TRANSB>: tiled 64x64 fp32 GEMM, optional bias/emul/relu/accum
//   softmax_dim1:     softmax over i (axis=1) for each (b, j)
//   gru_kernel:       1 workgroup per batch, whh held in VGPRs as f16,
//                     v_dot2_f32_f16 inner product, 512 sequential steps
// ---------------------------------------------------------------------------

typedef _Float16 h2 __attribute__((ext_vector_type(2)));
struct alignas(16) H2x4 { h2 a, b, c, d; };

#if __has_builtin(__builtin_amdgcn_fdot2)
#define FDOT2(a, b, c) __builtin_amdgcn_fdot2((a), (b), (c), false)
#else
#define FDOT2(a, b, c) ((c) + (float)(a)[0] * (float)(b)[0] + (float)(a)[1] * (float)(b)[1])
#endif

#define BM 64
#define BN 64
#define BK 16

template <bool TRANSB>
__global__ __launch_bounds__(256) void gemm_f32(
    const float* __restrict__ A, int lda, long long sA,
    const float* __restrict__ B, int ldb, long long sB,
    float* __restrict__ C, int ldc, long long sC,
    int M, int N, int K,
    const float* __restrict__ bias,
    const float* __restrict__ emul, int ldmul,
    int relu, int accum)
{
    __shared__ float As[BK][BM + 4];
    __shared__ float Bs[BK][BN + 4];

    const int tid = threadIdx.x;
    const int tx = tid & 15, ty = tid >> 4;
    const int m0 = blockIdx.y * BM, n0 = blockIdx.x * BN;

    const float* Ab = A + (size_t)blockIdx.z * sA;
    const float* Bb = B + (size_t)blockIdx.z * sB;
    float* Cb = C + (size_t)blockIdx.z * sC;

    float acc[4][4] = {};

    const int ar = tid >> 2;            // 0..63
    const int akg = (tid & 3) * 4;      // 0,4,8,12

    for (int k0 = 0; k0 < K; k0 += BK) {
        float4 av = *(const float4*)(Ab + (size_t)(m0 + ar) * lda + k0 + akg);
        As[akg + 0][ar] = av.x;
        As[akg + 1][ar] = av.y;
        As[akg + 2][ar] = av.z;
        As[akg + 3][ar] = av.w;
        if constexpr (TRANSB) {
            // B is [N, K] row-major (C = A * B^T)
            float4 bv = *(const float4*)(Bb + (size_t)(n0 + ar) * ldb + k0 + akg);
            Bs[akg + 0][ar] = bv.x;
            Bs[akg + 1][ar] = bv.y;
            Bs[akg + 2][ar] = bv.z;
            Bs[akg + 3][ar] = bv.w;
        } else {
            // B is [K, N] row-major (C = A * B)
            const int bk = tid >> 4;          // 0..15
            const int bng = (tid & 15) * 4;   // 0..60
            float4 bv = *(const float4*)(Bb + (size_t)(k0 + bk) * ldb + n0 + bng);
            *(float4*)&Bs[bk][bng] = bv;
        }
        __syncthreads();

#pragma unroll
        for (int k = 0; k < BK; ++k) {
            float a4[4], b4[4];
            *(float4*)a4 = *(const float4*)&As[k][4 * ty];
            *(float4*)b4 = *(const float4*)&Bs[k][4 * tx];
#pragma unroll
            for (int i = 0; i < 4; ++i)
#pragma unroll
                for (int j = 0; j < 4; ++j)
                    acc[i][j] += a4[i] * b4[j];
        }
        __syncthreads();
    }

#pragma unroll
    for (int i = 0; i < 4; ++i) {
        const int m = m0 + 4 * ty + i;
#pragma unroll
        for (int j = 0; j < 4; ++j) {
            const int n = n0 + 4 * tx + j;
            float v = acc[i][j];
            if (bias) v += bias[n];
            if (accum) v += Cb[(size_t)m * ldc + n];
            if (emul) v *= emul[(size_t)m * ldmul + n];
            if (relu) v = fmaxf(v, 0.f);
            Cb[(size_t)m * ldc + n] = v;
        }
    }
}

// softmax over axis=1 (the i / L1 axis): for each (b, j) normalize column i.
__global__ __launch_bounds__(256) void softmax_dim1(float* __restrict__ Mb)
{
    const int j = blockIdx.x * 256 + threadIdx.x;   // 0..511
    float* base = Mb + (size_t)blockIdx.y * 512 * 512;

    float mx = -1e30f;
    for (int i = 0; i < 512; ++i)
        mx = fmaxf(mx, base[(size_t)i * 512 + j]);
    float s = 0.f;
    for (int i = 0; i < 512; ++i) {
        float e = expf(base[(size_t)i * 512 + j] - mx);
        base[(size_t)i * 512 + j] = e;
        s += e;
    }
    const float inv = 1.f / s;
    for (int i = 0; i < 512; ++i)
        base[(size_t)i * 512 + j] *= inv;
}

__device__ __forceinline__ float sigmoidf_(float x) { return 1.f / (1.f + expf(-x)); }

// One workgroup per batch. 768 threads; thread o owns whh row o (f16-packed in
// VGPRs). Threads 0..127 own hidden dims {2o, 2o+1} for the gate/elementwise.
__global__ __launch_bounds__(768, 1) void gru_kernel(
    const float* __restrict__ xproj,   // [B, T, 768]
    const float* __restrict__ whh,     // [768, 256]
    const float* __restrict__ bhh,     // [768]
    float* __restrict__ out)           // [B, T, 256]
{
    const int b = blockIdx.x;
    const int o = threadIdx.x;

    __shared__ __align__(16) h2 hh[128];   // h state, f16-packed (matmul input)
    __shared__ float hp[768];              // h @ whh^T + bhh

    // Preload weight row o into registers as 128 packed half2.
    h2 w[128];
    {
        const float4* wr = (const float4*)(whh + (size_t)o * 256);
#pragma unroll
        for (int k = 0; k < 64; ++k) {
            float4 v = wr[k];
            h2 p0, p1;
            p0[0] = (_Float16)v.x; p0[1] = (_Float16)v.y;
            p1[0] = (_Float16)v.z; p1[1] = (_Float16)v.w;
            w[2 * k + 0] = p0;
            w[2 * k + 1] = p1;
        }
    }
    const float bias_o = bhh[o];
    float hA = 0.f, hB = 0.f;    // fp32 h state for dims 2o, 2o+1 (o < 128)
    if (o < 128) {
        h2 z; z[0] = (_Float16)0.f; z[1] = (_Float16)0.f;
        hh[o] = z;
    }
    __syncthreads();

    for (int t = 0; t < 512; ++t) {
        // hp[o] = bhh[o] + whh[o,:] . h
        float acc = bias_o;
        const H2x4* hv = (const H2x4*)hh;
#pragma unroll
        for (int k = 0; k < 32; ++k) {
            H2x4 v = hv[k];
            acc = FDOT2(w[4 * k + 0], v.a, acc);
            acc = FDOT2(w[4 * k + 1], v.b, acc);
            acc = FDOT2(w[4 * k + 2], v.c, acc);
            acc = FDOT2(w[4 * k + 3], v.d, acc);
        }
        hp[o] = acc;
        __syncthreads();

        if (o < 128) {
            const float* xb = xproj + ((size_t)b * 512 + t) * 768;
            float2 xr = ((const float2*)xb)[o];
            float2 xz = ((const float2*)(xb + 256))[o];
            float2 xn = ((const float2*)(xb + 512))[o];
            float2 hr = *(const float2*)&hp[2 * o];
            float2 hz = *(const float2*)&hp[256 + 2 * o];
            float2 hn = *(const float2*)&hp[512 + 2 * o];

            float r0 = sigmoidf_(xr.x + hr.x), r1 = sigmoidf_(xr.y + hr.y);
            float z0 = sigmoidf_(xz.x + hz.x), z1 = sigmoidf_(xz.y + hz.y);
            float n0 = tanhf(xn.x + r0 * hn.x), n1 = tanhf(xn.y + r1 * hn.y);
            float nh0 = (1.f - z0) * n0 + z0 * hA;
            float nh1 = (1.f - z1) * n1 + z1 * hB;
            hA = nh0; hB = nh1;

            h2 p; p[0] = (_Float16)nh0; p[1] = (_Float16)nh1;
            hh[o] = p;
            ((float2*)(out + ((size_t)b * 512 + t) * 256))[o] = make_float2(nh0, nh1);
        }
        __syncthreads();
    }
}

extern "C" void kernel_launch(void* const* d_in, const int* in_sizes, int n_in,
                              void* d_out, int out_size, void* d_ws, size_t ws_size,
                              hipStream_t stream)
{
    (void)in_sizes; (void)n_in; (void)out_size; (void)ws_size;

    const float* x1  = (const float*)d_in[0];   // [32, 512, 256]
    const float* x2  = (const float*)d_in[1];   // [32, 512, 256]
    const float* w1  = (const float*)d_in[2];   // [256, 256]
    const float* w2  = (const float*)d_in[3];   // [256, 256]
    const float* Dm  = (const float*)d_in[4];   // [256, 256]
    const float* Wm  = (const float*)d_in[5];   // [512, 512]
    const float* wih = (const float*)d_in[6];   // [768, 512]
    const float* whh = (const float*)d_in[7];   // [768, 256]
    const float* bih = (const float*)d_in[8];   // [768]
    const float* bhh = (const float*)d_in[9];   // [768]
    float* out = (float*)d_out;                 // [32, 512, 256]
    float* ws = (float*)d_ws;

    // workspace layout (floats):
    float* a1  = ws;                 // 4194304   [B*L1, A]
    float* a2  = ws + 4194304;       // 4194304   [B*L2, A]
    float* a1d = ws + 8388608;       // 4194304   [B*L1, A]
    float* Mb  = ws + 12582912;      // 8388608   [B, L1, L2]
    float* ctx = a1;                 // reuse (a1 dead after a1d)
    float* xp  = ws + 8388608;       // 12582912  [B*L1, 768] (overlays a1d+Mb)

    dim3 blk(256);

    // a1 = relu(x1 @ w1^T)            M=16384 N=256 K=256
    gemm_f32<true><<<dim3(4, 256, 1), blk, 0, stream>>>(
        x1, 256, 0, w1, 256, 0, a1, 256, 0, 16384, 256, 256,
        nullptr, nullptr, 0, 1, 0);
    // a2 = relu(x2 @ w2^T)
    gemm_f32<true><<<dim3(4, 256, 1), blk, 0, stream>>>(
        x2, 256, 0, w2, 256, 0, a2, 256, 0, 16384, 256, 256,
        nullptr, nullptr, 0, 1, 0);
    // a1d = a1 @ D                    (NN)
    gemm_f32<false><<<dim3(4, 256, 1), blk, 0, stream>>>(
        a1, 256, 0, Dm, 256, 0, a1d, 256, 0, 16384, 256, 256,
        nullptr, nullptr, 0, 0, 0);
    // M[b] = (a1d[b] @ a2[b]^T) * W   M=512 N=512 K=256, batch=32
    gemm_f32<true><<<dim3(8, 8, 32), blk, 0, stream>>>(
        a1d, 256, 131072, a2, 256, 131072, Mb, 512, 262144, 512, 512, 256,
        nullptr, Wm, 512, 0, 0);
    // softmax over i for each (b, j)
    softmax_dim1<<<dim3(2, 32), blk, 0, stream>>>(Mb);
    // ctx[b] = M[b] @ x2[b]           (NN) M=512 N=256 K=512, batch=32
    gemm_f32<false><<<dim3(4, 8, 32), blk, 0, stream>>>(
        Mb, 512, 262144, x2, 256, 131072, ctx, 256, 131072, 512, 256, 512,
        nullptr, nullptr, 0, 0, 0);
    // xp = x1 @ wih[:, :256]^T + bih  M=16384 N=768 K=256
    gemm_f32<true><<<dim3(12, 256, 1), blk, 0, stream>>>(
        x1, 256, 0, wih, 512, 0, xp, 768, 0, 16384, 768, 256,
        bih, nullptr, 0, 0, 0);
    // xp += ctx @ wih[:, 256:]^T
    gemm_f32<true><<<dim3(12, 256, 1), blk, 0, stream>>>(
        ctx, 256, 0, wih + 256, 512, 0, xp, 768, 0, 16384, 768, 256,
        nullptr, nullptr, 0, 0, 1);
    // GRU recurrence: 1 WG per batch
    gru_kernel<<<dim3(32), dim3(768), 0, stream>>>(xp, whh, bhh, out);
}

// Round 2
// 1371.908 us; speedup vs baseline: 1.1408x; 1.1408x over previous
//
#include <hip/hip_runtime.h>
#include <cstdint>
#include <cstddef>

// ---------------------------------------------------------------------------
// EnrichAttention: B=32, L1=L2=512, H=A=256, 3H=768, 2H=512
// R2: GRU rewrite — force whh register-residency (waves_per_eu(3,3), chunked
//     preload), LDS-only barriers, xproj prefetch, 4-way accum ILP.
// ---------------------------------------------------------------------------

typedef _Float16 h2 __attribute__((ext_vector_type(2)));
struct alignas(16) H2x4 { h2 a, b, c, d; };

#if __has_builtin(__builtin_amdgcn_fdot2)
#define FDOT2(a, b, c) __builtin_amdgcn_fdot2((a), (b), (c), false)
#else
#define FDOT2(a, b, c) ((c) + (float)(a)[0] * (float)(b)[0] + (float)(a)[1] * (float)(b)[1])
#endif

#if __has_builtin(__builtin_amdgcn_sched_barrier)
#define SCHED_FENCE() __builtin_amdgcn_sched_barrier(0)
#else
#define SCHED_FENCE() asm volatile("" ::: "memory")
#endif

// Workgroup barrier that waits only on LDS (lgkmcnt), leaving global loads
// and stores in flight. Safe here: only hh/hp (LDS) carry inter-wave deps.
__device__ __forceinline__ void bar_lds() {
    asm volatile("s_waitcnt lgkmcnt(0)\n\ts_barrier" ::: "memory");
}

__device__ __forceinline__ float fast_exp(float x) {
#if __has_builtin(__builtin_amdgcn_exp2f)
    return __builtin_amdgcn_exp2f(x * 1.44269504f);
#else
    return __expf(x);
#endif
}
__device__ __forceinline__ float fast_rcp(float x) {
#if __has_builtin(__builtin_amdgcn_rcpf)
    return __builtin_amdgcn_rcpf(x);
#else
    return 1.f / x;
#endif
}
__device__ __forceinline__ float fast_sig(float x) { return fast_rcp(1.f + fast_exp(-x)); }
__device__ __forceinline__ float fast_tanh(float x) {
    // tanh(x) = 1 - 2/(1+e^{2x}); correct limits at +/-inf
    return 1.f - 2.f * fast_rcp(1.f + fast_exp(2.f * x));
}

#define BM 64
#define BN 64
#define BK 16

template <bool TRANSB>
__global__ __launch_bounds__(256) void gemm_f32(
    const float* __restrict__ A, int lda, long long sA,
    const float* __restrict__ B, int ldb, long long sB,
    float* __restrict__ C, int ldc, long long sC,
    int M, int N, int K,
    const float* __restrict__ bias,
    const float* __restrict__ emul, int ldmul,
    int relu, int accum)
{
    __shared__ float As[BK][BM + 4];
    __shared__ float Bs[BK][BN + 4];

    const int tid = threadIdx.x;
    const int tx = tid & 15, ty = tid >> 4;
    const int m0 = blockIdx.y * BM, n0 = blockIdx.x * BN;

    const float* Ab = A + (size_t)blockIdx.z * sA;
    const float* Bb = B + (size_t)blockIdx.z * sB;
    float* Cb = C + (size_t)blockIdx.z * sC;

    float acc[4][4] = {};

    const int ar = tid >> 2;            // 0..63
    const int akg = (tid & 3) * 4;      // 0,4,8,12

    for (int k0 = 0; k0 < K; k0 += BK) {
        float4 av = *(const float4*)(Ab + (size_t)(m0 + ar) * lda + k0 + akg);
        As[akg + 0][ar] = av.x;
        As[akg + 1][ar] = av.y;
        As[akg + 2][ar] = av.z;
        As[akg + 3][ar] = av.w;
        if constexpr (TRANSB) {
            float4 bv = *(const float4*)(Bb + (size_t)(n0 + ar) * ldb + k0 + akg);
            Bs[akg + 0][ar] = bv.x;
            Bs[akg + 1][ar] = bv.y;
            Bs[akg + 2][ar] = bv.z;
            Bs[akg + 3][ar] = bv.w;
        } else {
            const int bk = tid >> 4;
            const int bng = (tid & 15) * 4;
            float4 bv = *(const float4*)(Bb + (size_t)(k0 + bk) * ldb + n0 + bng);
            *(float4*)&Bs[bk][bng] = bv;
        }
        __syncthreads();

#pragma unroll
        for (int k = 0; k < BK; ++k) {
            float a4[4], b4[4];
            *(float4*)a4 = *(const float4*)&As[k][4 * ty];
            *(float4*)b4 = *(const float4*)&Bs[k][4 * tx];
#pragma unroll
            for (int i = 0; i < 4; ++i)
#pragma unroll
                for (int j = 0; j < 4; ++j)
                    acc[i][j] += a4[i] * b4[j];
        }
        __syncthreads();
    }

#pragma unroll
    for (int i = 0; i < 4; ++i) {
        const int m = m0 + 4 * ty + i;
#pragma unroll
        for (int j = 0; j < 4; ++j) {
            const int n = n0 + 4 * tx + j;
            float v = acc[i][j];
            if (bias) v += bias[n];
            if (accum) v += Cb[(size_t)m * ldc + n];
            if (emul) v *= emul[(size_t)m * ldmul + n];
            if (relu) v = fmaxf(v, 0.f);
            Cb[(size_t)m * ldc + n] = v;
        }
    }
}

__global__ __launch_bounds__(256) void softmax_dim1(float* __restrict__ Mb)
{
    const int j = blockIdx.x * 256 + threadIdx.x;
    float* base = Mb + (size_t)blockIdx.y * 512 * 512;

    float mx = -1e30f;
    for (int i = 0; i < 512; ++i)
        mx = fmaxf(mx, base[(size_t)i * 512 + j]);
    float s = 0.f;
    for (int i = 0; i < 512; ++i) {
        float e = __expf(base[(size_t)i * 512 + j] - mx);
        base[(size_t)i * 512 + j] = e;
        s += e;
    }
    const float inv = 1.f / s;
    for (int i = 0; i < 512; ++i)
        base[(size_t)i * 512 + j] *= inv;
}

// One workgroup per batch (32 WGs). 768 threads; thread o owns whh row o as
// 128 packed half2 in VGPRs. 12 waves = 3 waves/SIMD -> 170-VGPR budget.
__global__
__attribute__((amdgpu_flat_work_group_size(768, 768)))
__attribute__((amdgpu_waves_per_eu(3, 3)))
void gru_kernel(
    const float* __restrict__ xproj,   // [B, T, 768]
    const float* __restrict__ whh,     // [768, 256]
    const float* __restrict__ bhh,     // [768]
    float* __restrict__ out)           // [B, T, 256]
{
    const int b = blockIdx.x;
    const int o = threadIdx.x;

    __shared__ __align__(16) h2 hh[128];   // h state, f16-packed
    __shared__ float hp[768];              // h @ whh^T + bhh

    // ---- preload whh row o -> 128 half2 VGPRs, in pressure-bounded chunks
    h2 w[128];
    {
        const float4* wr = (const float4*)(whh + (size_t)o * 256);
#pragma unroll
        for (int c = 0; c < 16; ++c) {
            float4 t0 = wr[4 * c + 0];
            float4 t1 = wr[4 * c + 1];
            float4 t2 = wr[4 * c + 2];
            float4 t3 = wr[4 * c + 3];
            h2 p;
            p[0] = (_Float16)t0.x; p[1] = (_Float16)t0.y; w[8 * c + 0] = p;
            p[0] = (_Float16)t0.z; p[1] = (_Float16)t0.w; w[8 * c + 1] = p;
            p[0] = (_Float16)t1.x; p[1] = (_Float16)t1.y; w[8 * c + 2] = p;
            p[0] = (_Float16)t1.z; p[1] = (_Float16)t1.w; w[8 * c + 3] = p;
            p[0] = (_Float16)t2.x; p[1] = (_Float16)t2.y; w[8 * c + 4] = p;
            p[0] = (_Float16)t2.z; p[1] = (_Float16)t2.w; w[8 * c + 5] = p;
            p[0] = (_Float16)t3.x; p[1] = (_Float16)t3.y; w[8 * c + 6] = p;
            p[0] = (_Float16)t3.z; p[1] = (_Float16)t3.w; w[8 * c + 7] = p;
            SCHED_FENCE();
        }
    }
    const float bias_o = bhh[o];
    const float* xb_base = xproj + (size_t)b * 512 * 768;

    float hA = 0.f, hB = 0.f;
    float2 xr, xz, xn;                 // prefetched x-gate inputs for step t
    if (o < 128) {
        h2 z; z[0] = (_Float16)0.f; z[1] = (_Float16)0.f;
        hh[o] = z;
        const float2* r0 = (const float2*)xb_base;
        xr = r0[o]; xz = r0[128 + o]; xn = r0[256 + o];
    }
    bar_lds();

    for (int t = 0; t < 512; ++t) {
        // hp[o] = bhh[o] + whh[o,:] . h   (4 accumulators for ILP)
        float a0 = bias_o, a1 = 0.f, a2 = 0.f, a3 = 0.f;
        const H2x4* hv = (const H2x4*)hh;
#pragma unroll
        for (int k = 0; k < 32; ++k) {
            H2x4 v = hv[k];
            a0 = FDOT2(w[4 * k + 0], v.a, a0);
            a1 = FDOT2(w[4 * k + 1], v.b, a1);
            a2 = FDOT2(w[4 * k + 2], v.c, a2);
            a3 = FDOT2(w[4 * k + 3], v.d, a3);
        }
        hp[o] = (a0 + a1) + (a2 + a3);
        bar_lds();

        if (o < 128) {
            // issue prefetch for step t+1 (wrap keeps it in-bounds & uniform)
            const int tn = (t + 1) & 511;
            const float2* rn = (const float2*)(xb_base + (size_t)tn * 768);
            float2 nr = rn[o], nz = rn[128 + o], nn = rn[256 + o];

            float2 hr = *(const float2*)&hp[2 * o];
            float2 hz = *(const float2*)&hp[256 + 2 * o];
            float2 hn = *(const float2*)&hp[512 + 2 * o];

            float r0 = fast_sig(xr.x + hr.x), r1 = fast_sig(xr.y + hr.y);
            float z0 = fast_sig(xz.x + hz.x), z1 = fast_sig(xz.y + hz.y);
            float n0 = fast_tanh(xn.x + r0 * hn.x), n1 = fast_tanh(xn.y + r1 * hn.y);
            float nh0 = (1.f - z0) * n0 + z0 * hA;
            float nh1 = (1.f - z1) * n1 + z1 * hB;
            hA = nh0; hB = nh1;

            h2 p; p[0] = (_Float16)nh0; p[1] = (_Float16)nh1;
            hh[o] = p;
            ((float2*)(out + ((size_t)b * 512 + t) * 256))[o] = make_float2(nh0, nh1);

            xr = nr; xz = nz; xn = nn;
        }
        bar_lds();
    }
}

extern "C" void kernel_launch(void* const* d_in, const int* in_sizes, int n_in,
                              void* d_out, int out_size, void* d_ws, size_t ws_size,
                              hipStream_t stream)
{
    (void)in_sizes; (void)n_in; (void)out_size; (void)ws_size;

    const float* x1  = (const float*)d_in[0];
    const float* x2  = (const float*)d_in[1];
    const float* w1  = (const float*)d_in[2];
    const float* w2  = (const float*)d_in[3];
    const float* Dm  = (const float*)d_in[4];
    const float* Wm  = (const float*)d_in[5];
    const float* wih = (const float*)d_in[6];
    const float* whh = (const float*)d_in[7];
    const float* bih = (const float*)d_in[8];
    const float* bhh = (const float*)d_in[9];
    float* out = (float*)d_out;
    float* ws = (float*)d_ws;

    float* a1  = ws;                 // [B*L1, A]
    float* a2  = ws + 4194304;       // [B*L2, A]
    float* a1d = ws + 8388608;       // [B*L1, A]
    float* Mb  = ws + 12582912;      // [B, L1, L2]
    float* ctx = a1;                 // reuse
    float* xp  = ws + 8388608;       // [B*L1, 768] (overlays a1d+Mb)

    dim3 blk(256);

    gemm_f32<true><<<dim3(4, 256, 1), blk, 0, stream>>>(
        x1, 256, 0, w1, 256, 0, a1, 256, 0, 16384, 256, 256,
        nullptr, nullptr, 0, 1, 0);
    gemm_f32<true><<<dim3(4, 256, 1), blk, 0, stream>>>(
        x2, 256, 0, w2, 256, 0, a2, 256, 0, 16384, 256, 256,
        nullptr, nullptr, 0, 1, 0);
    gemm_f32<false><<<dim3(4, 256, 1), blk, 0, stream>>>(
        a1, 256, 0, Dm, 256, 0, a1d, 256, 0, 16384, 256, 256,
        nullptr, nullptr, 0, 0, 0);
    gemm_f32<true><<<dim3(8, 8, 32), blk, 0, stream>>>(
        a1d, 256, 131072, a2, 256, 131072, Mb, 512, 262144, 512, 512, 256,
        nullptr, Wm, 512, 0, 0);
    softmax_dim1<<<dim3(2, 32), blk, 0, stream>>>(Mb);
    gemm_f32<false><<<dim3(4, 8, 32), blk, 0, stream>>>(
        Mb, 512, 262144, x2, 256, 131072, ctx, 256, 131072, 512, 256, 512,
        nullptr, nullptr, 0, 0, 0);
    gemm_f32<true><<<dim3(12, 256, 1), blk, 0, stream>>>(
        x1, 256, 0, wih, 512, 0, xp, 768, 0, 16384, 768, 256,
        bih, nullptr, 0, 0, 0);
    gemm_f32<true><<<dim3(12, 256, 1), blk, 0, stream>>>(
        ctx, 256, 0, wih + 256, 512, 0, xp, 768, 0, 16384, 768, 256,
        nullptr, nullptr, 0, 0, 1);
    gru_kernel<<<dim3(32), dim3(768), 0, stream>>>(xp, whh, bhh, out);
}

// Round 5
// 1110.101 us; speedup vs baseline: 1.4098x; 1.2358x over previous
//
#include <hip/hip_runtime.h>
#include <hip/hip_bf16.h>
#include <cstdint>
#include <cstddef>

// ---------------------------------------------------------------------------
// EnrichAttention: B=32, L1=L2=512, H=A=256, 3H=768, 2H=512
// R5: GEMMs -> MFMA bf16 (16x16x32, verified fragment layouts); GRU = exact
//     R2 kernel (proven pass @728us). fp32 accumulate everywhere.
// ---------------------------------------------------------------------------

typedef _Float16 h2 __attribute__((ext_vector_type(2)));
typedef short s8v __attribute__((ext_vector_type(8)));    // 8 bf16 (4 VGPRs)
typedef float f4v __attribute__((ext_vector_type(4)));    // MFMA accumulator
struct alignas(16) H2x4 { h2 a, b, c, d; };

#if __has_builtin(__builtin_amdgcn_fdot2)
#define FDOT2(a, b, c) __builtin_amdgcn_fdot2((a), (b), (c), false)
#else
#define FDOT2(a, b, c) ((c) + (float)(a)[0] * (float)(b)[0] + (float)(a)[1] * (float)(b)[1])
#endif

#if __has_builtin(__builtin_amdgcn_sched_barrier)
#define SCHED_FENCE() __builtin_amdgcn_sched_barrier(0)
#else
#define SCHED_FENCE() asm volatile("" ::: "memory")
#endif

// Workgroup barrier waiting only on LDS (lgkmcnt). Only hh/hp (LDS) carry
// cross-thread deps in the GRU loop. (Validated in R2.)
__device__ __forceinline__ void bar_lds() {
    asm volatile("s_waitcnt lgkmcnt(0)\n\ts_barrier" ::: "memory");
}

__device__ __forceinline__ float fast_exp(float x) {
#if __has_builtin(__builtin_amdgcn_exp2f)
    return __builtin_amdgcn_exp2f(x * 1.44269504f);
#else
    return __expf(x);
#endif
}
__device__ __forceinline__ float fast_rcp(float x) {
#if __has_builtin(__builtin_amdgcn_rcpf)
    return __builtin_amdgcn_rcpf(x);
#else
    return 1.f / x;
#endif
}
__device__ __forceinline__ float fast_sig(float x) { return fast_rcp(1.f + fast_exp(-x)); }
__device__ __forceinline__ float fast_tanh(float x) {
    return 1.f - 2.f * fast_rcp(1.f + fast_exp(2.f * x));
}

// ---------------------------------------------------------------------------
// MFMA bf16 NT GEMM: C[M,N] = A[M,K] * B[N,K]^T, A/B bf16, C fp32 or bf16.
// 128x128 block, 4 waves (2x2 of 64x64), BK=32, one mfma_16x16x32 per tile.
// Layouts (HW-verified): A/B frag: lane holds row(m|n)=lane&15, k=quad*8+j.
// C/D frag: col=lane&15, row=quad*4+reg.
// ---------------------------------------------------------------------------
__global__ __launch_bounds__(256) void gemm_bf16(
    const __hip_bfloat16* __restrict__ A, int lda, long long sA,
    const __hip_bfloat16* __restrict__ B, int ldb, long long sB,
    void* __restrict__ C, int ldc, long long sC,
    int K,
    const float* __restrict__ bias,
    const float* __restrict__ emul, int ldmul,
    int relu, int accum, int out_bf16)
{
    __shared__ short As[128][40];   // 32 + 8 pad (keeps b128 reads 2-way max)
    __shared__ short Bs[128][40];

    const int tid  = threadIdx.x;
    const int wave = tid >> 6, lane = tid & 63;
    const int quad = lane >> 4, l16 = lane & 15;
    const int wrow = (wave >> 1) * 64, wcol = (wave & 1) * 64;
    const int m0 = blockIdx.y * 128, n0 = blockIdx.x * 128;

    const short* Ab = (const short*)A + (size_t)blockIdx.z * sA;
    const short* Bb = (const short*)B + (size_t)blockIdx.z * sB;

    f4v acc[4][4];
#pragma unroll
    for (int i = 0; i < 4; ++i)
#pragma unroll
        for (int j = 0; j < 4; ++j) acc[i][j] = 0.f;

    // staging: 512 chunks of 8 bf16; thread t does chunks t and t+256
    const int r0 = tid >> 2,        s0 = (tid & 3) * 8;
    const int r1 = (tid + 256) >> 2, s1 = ((tid + 256) & 3) * 8;

    for (int k0 = 0; k0 < K; k0 += 32) {
        *(s8v*)&As[r0][s0] = *(const s8v*)(Ab + (size_t)(m0 + r0) * lda + k0 + s0);
        *(s8v*)&As[r1][s1] = *(const s8v*)(Ab + (size_t)(m0 + r1) * lda + k0 + s1);
        *(s8v*)&Bs[r0][s0] = *(const s8v*)(Bb + (size_t)(n0 + r0) * ldb + k0 + s0);
        *(s8v*)&Bs[r1][s1] = *(const s8v*)(Bb + (size_t)(n0 + r1) * ldb + k0 + s1);
        __syncthreads();

        s8v af[4], bf[4];
#pragma unroll
        for (int i = 0; i < 4; ++i)
            af[i] = *(const s8v*)&As[wrow + i * 16 + l16][quad * 8];
#pragma unroll
        for (int j = 0; j < 4; ++j)
            bf[j] = *(const s8v*)&Bs[wcol + j * 16 + l16][quad * 8];
#pragma unroll
        for (int i = 0; i < 4; ++i)
#pragma unroll
            for (int j = 0; j < 4; ++j)
                acc[i][j] = __builtin_amdgcn_mfma_f32_16x16x32_bf16(
                    af[i], bf[j], acc[i][j], 0, 0, 0);
        __syncthreads();
    }

    float* Cf = (float*)C + (size_t)blockIdx.z * sC;
    __hip_bfloat16* Cb = (__hip_bfloat16*)C + (size_t)blockIdx.z * sC;
#pragma unroll
    for (int i = 0; i < 4; ++i)
#pragma unroll
        for (int j = 0; j < 4; ++j)
#pragma unroll
            for (int r = 0; r < 4; ++r) {
                const int m = m0 + wrow + i * 16 + quad * 4 + r;
                const int n = n0 + wcol + j * 16 + l16;
                float v = acc[i][j][r];
                if (bias)  v += bias[n];
                if (accum) v += Cf[(size_t)m * ldc + n];
                if (emul)  v *= emul[(size_t)m * ldmul + n];
                if (relu)  v = fmaxf(v, 0.f);
                if (out_bf16) Cb[(size_t)m * ldc + n] = __float2bfloat16(v);
                else          Cf[(size_t)m * ldc + n] = v;
            }
}

// fp32 -> bf16 elementwise (n % 4 == 0)
__global__ __launch_bounds__(256) void f2b(
    const float* __restrict__ s, __hip_bfloat16* __restrict__ d, int n)
{
    const int i = (blockIdx.x * 256 + threadIdx.x) * 4;
    if (i < n) {
        float4 v = *(const float4*)(s + i);
        d[i + 0] = __float2bfloat16(v.x);
        d[i + 1] = __float2bfloat16(v.y);
        d[i + 2] = __float2bfloat16(v.z);
        d[i + 3] = __float2bfloat16(v.w);
    }
}

// fp32 [Z][R][C] -> bf16 [Z][C][R] tiled transpose
__global__ __launch_bounds__(256) void tr_f2b(
    const float* __restrict__ src, __hip_bfloat16* __restrict__ dst,
    int R, int C, long long sS, long long sD)
{
    __shared__ float t[32][33];
    const int r0 = blockIdx.y * 32, c0 = blockIdx.x * 32;
    const int tx = threadIdx.x & 31, ty = threadIdx.x >> 5;   // ty 0..7
    const float* S = src + (size_t)blockIdx.z * sS;
    __hip_bfloat16* Dd = dst + (size_t)blockIdx.z * sD;
#pragma unroll
    for (int i = 0; i < 32; i += 8)
        t[ty + i][tx] = S[(size_t)(r0 + ty + i) * C + c0 + tx];
    __syncthreads();
#pragma unroll
    for (int i = 0; i < 32; i += 8)
        Dd[(size_t)(c0 + ty + i) * R + r0 + tx] = __float2bfloat16(t[tx][ty + i]);
}

// softmax over axis=1 (i) for each (b, j): fp32 in, bf16 out
__global__ __launch_bounds__(256) void softmax_dim1(
    const float* __restrict__ Mf, __hip_bfloat16* __restrict__ Ms)
{
    const int j = blockIdx.x * 256 + threadIdx.x;
    const float* base = Mf + (size_t)blockIdx.y * 262144;
    __hip_bfloat16* ob = Ms + (size_t)blockIdx.y * 262144;

    float mx = -1e30f;
    for (int i = 0; i < 512; ++i)
        mx = fmaxf(mx, base[(size_t)i * 512 + j]);
    float s = 0.f;
    for (int i = 0; i < 512; ++i)
        s += __expf(base[(size_t)i * 512 + j] - mx);
    const float inv = 1.f / s;
    for (int i = 0; i < 512; ++i)
        ob[(size_t)i * 512 + j] =
            __float2bfloat16(__expf(base[(size_t)i * 512 + j] - mx) * inv);
}

// ---------------------------------------------------------------------------
// GRU: exact R2 kernel (proven pass @728us). One WG per batch, 768 threads,
// whh row in h2 w[128] (scratch/L1-resident), lgkm-only barriers, prefetch.
// ---------------------------------------------------------------------------
__global__
__attribute__((amdgpu_flat_work_group_size(768, 768)))
__attribute__((amdgpu_waves_per_eu(3, 3)))
void gru_kernel(
    const float* __restrict__ xproj,   // [B, T, 768]
    const float* __restrict__ whh,     // [768, 256]
    const float* __restrict__ bhh,     // [768]
    float* __restrict__ out)           // [B, T, 256]
{
    const int b = blockIdx.x;
    const int o = threadIdx.x;

    __shared__ __align__(16) h2 hh[128];
    __shared__ float hp[768];

    h2 w[128];
    {
        const float4* wr = (const float4*)(whh + (size_t)o * 256);
#pragma unroll
        for (int c = 0; c < 16; ++c) {
            float4 t0 = wr[4 * c + 0];
            float4 t1 = wr[4 * c + 1];
            float4 t2 = wr[4 * c + 2];
            float4 t3 = wr[4 * c + 3];
            h2 p;
            p[0] = (_Float16)t0.x; p[1] = (_Float16)t0.y; w[8 * c + 0] = p;
            p[0] = (_Float16)t0.z; p[1] = (_Float16)t0.w; w[8 * c + 1] = p;
            p[0] = (_Float16)t1.x; p[1] = (_Float16)t1.y; w[8 * c + 2] = p;
            p[0] = (_Float16)t1.z; p[1] = (_Float16)t1.w; w[8 * c + 3] = p;
            p[0] = (_Float16)t2.x; p[1] = (_Float16)t2.y; w[8 * c + 4] = p;
            p[0] = (_Float16)t2.z; p[1] = (_Float16)t2.w; w[8 * c + 5] = p;
            p[0] = (_Float16)t3.x; p[1] = (_Float16)t3.y; w[8 * c + 6] = p;
            p[0] = (_Float16)t3.z; p[1] = (_Float16)t3.w; w[8 * c + 7] = p;
            SCHED_FENCE();
        }
    }
    const float bias_o = bhh[o];
    const float* xb_base = xproj + (size_t)b * 512 * 768;

    float hA = 0.f, hB = 0.f;
    float2 xr, xz, xn;
    if (o < 128) {
        h2 z; z[0] = (_Float16)0.f; z[1] = (_Float16)0.f;
        hh[o] = z;
        const float2* r0 = (const float2*)xb_base;
        xr = r0[o]; xz = r0[128 + o]; xn = r0[256 + o];
    }
    bar_lds();

    for (int t = 0; t < 512; ++t) {
        float a0 = bias_o, a1 = 0.f, a2 = 0.f, a3 = 0.f;
        const H2x4* hv = (const H2x4*)hh;
#pragma unroll
        for (int k = 0; k < 32; ++k) {
            H2x4 v = hv[k];
            a0 = FDOT2(w[4 * k + 0], v.a, a0);
            a1 = FDOT2(w[4 * k + 1], v.b, a1);
            a2 = FDOT2(w[4 * k + 2], v.c, a2);
            a3 = FDOT2(w[4 * k + 3], v.d, a3);
        }
        hp[o] = (a0 + a1) + (a2 + a3);
        bar_lds();

        if (o < 128) {
            const int tn = (t + 1) & 511;
            const float2* rn = (const float2*)(xb_base + (size_t)tn * 768);
            float2 nr = rn[o], nz = rn[128 + o], nn = rn[256 + o];

            float2 hr = *(const float2*)&hp[2 * o];
            float2 hz = *(const float2*)&hp[256 + 2 * o];
            float2 hn = *(const float2*)&hp[512 + 2 * o];

            float r0 = fast_sig(xr.x + hr.x), r1 = fast_sig(xr.y + hr.y);
            float z0 = fast_sig(xz.x + hz.x), z1 = fast_sig(xz.y + hz.y);
            float n0 = fast_tanh(xn.x + r0 * hn.x), n1 = fast_tanh(xn.y + r1 * hn.y);
            float nh0 = (1.f - z0) * n0 + z0 * hA;
            float nh1 = (1.f - z1) * n1 + z1 * hB;
            hA = nh0; hB = nh1;

            h2 p; p[0] = (_Float16)nh0; p[1] = (_Float16)nh1;
            hh[o] = p;
            ((float2*)(out + ((size_t)b * 512 + t) * 256))[o] = make_float2(nh0, nh1);

            xr = nr; xz = nz; xn = nn;
        }
        bar_lds();
    }
}

extern "C" void kernel_launch(void* const* d_in, const int* in_sizes, int n_in,
                              void* d_out, int out_size, void* d_ws, size_t ws_size,
                              hipStream_t stream)
{
    (void)in_sizes; (void)n_in; (void)out_size; (void)ws_size;

    const float* x1  = (const float*)d_in[0];   // [32,512,256]
    const float* x2  = (const float*)d_in[1];   // [32,512,256]
    const float* w1  = (const float*)d_in[2];   // [256,256]
    const float* w2  = (const float*)d_in[3];   // [256,256]
    const float* Dm  = (const float*)d_in[4];   // [256,256]
    const float* Wm  = (const float*)d_in[5];   // [512,512]
    const float* wih = (const float*)d_in[6];   // [768,512]
    const float* whh = (const float*)d_in[7];   // [768,256]
    const float* bih = (const float*)d_in[8];   // [768]
    const float* bhh = (const float*)d_in[9];   // [768]
    float* out = (float*)d_out;

    // Workspace: 80 MiB, lifetime-disjoint aliasing (verified against launch
    // order below; max offset 83886080 = footprint of the passing R1/R2).
    char* base = (char*)d_ws;
    __hip_bfloat16* w1b  = (__hip_bfloat16*)(base + 0);         // early
    __hip_bfloat16* w2b  = (__hip_bfloat16*)(base + 131072);    // early
    __hip_bfloat16* Dtb  = (__hip_bfloat16*)(base + 262144);    // early
    float*          Mf   = (float*)(base + 0);                  // M-gemm..softmax
    float*          xp   = (float*)(base + 0);                  // xp1..gru
    __hip_bfloat16* a1b  = (__hip_bfloat16*)(base + 33554432);  // a1..a1d
    __hip_bfloat16* a1db = (__hip_bfloat16*)(base + 41943040);  // a1d..M
    __hip_bfloat16* Msb  = (__hip_bfloat16*)(base + 33554432);  // softmax..ctx
    __hip_bfloat16* x1b  = (__hip_bfloat16*)(base + 50331648);  // ..xp1
    __hip_bfloat16* x2b  = (__hip_bfloat16*)(base + 58720256);  // ..a2
    __hip_bfloat16* ctxb = (__hip_bfloat16*)(base + 58720256);  // ctx..xp2
    __hip_bfloat16* x2tb = (__hip_bfloat16*)(base + 67108864);  // ..ctx
    __hip_bfloat16* a2b  = (__hip_bfloat16*)(base + 75497472);  // ..M
    __hip_bfloat16* wihb = (__hip_bfloat16*)(base + 75497472);  // post-M..xp2

    dim3 blk(256);

    // converts
    f2b<<<dim3(4096), blk, 0, stream>>>(x1, x1b, 4194304);
    f2b<<<dim3(4096), blk, 0, stream>>>(x2, x2b, 4194304);
    f2b<<<dim3(64),   blk, 0, stream>>>(w1, w1b, 65536);
    f2b<<<dim3(64),   blk, 0, stream>>>(w2, w2b, 65536);
    tr_f2b<<<dim3(8, 16, 32), blk, 0, stream>>>(x2, x2tb, 512, 256, 131072, 131072);
    tr_f2b<<<dim3(8, 8, 1),   blk, 0, stream>>>(Dm, Dtb, 256, 256, 0, 0);

    // a1 = relu(x1 @ w1^T)  [16384,256] bf16 out
    gemm_bf16<<<dim3(2, 128, 1), blk, 0, stream>>>(
        x1b, 256, 0, w1b, 256, 0, a1b, 256, 0, 256,
        nullptr, nullptr, 0, 1, 0, 1);
    // a2 = relu(x2 @ w2^T)
    gemm_bf16<<<dim3(2, 128, 1), blk, 0, stream>>>(
        x2b, 256, 0, w2b, 256, 0, a2b, 256, 0, 256,
        nullptr, nullptr, 0, 1, 0, 1);
    // a1d = a1 @ D  (NT with Dtb = D^T)
    gemm_bf16<<<dim3(2, 128, 1), blk, 0, stream>>>(
        a1b, 256, 0, Dtb, 256, 0, a1db, 256, 0, 256,
        nullptr, nullptr, 0, 0, 0, 1);
    // Mf[b] = (a1d[b] @ a2[b]^T) * W   fp32 out
    gemm_bf16<<<dim3(4, 4, 32), blk, 0, stream>>>(
        a1db, 256, 131072, a2b, 256, 131072, Mf, 512, 262144, 256,
        nullptr, Wm, 512, 0, 0, 0);
    // wihb convert (a2b dead after M-gemm; wihb aliases it)
    f2b<<<dim3(384), blk, 0, stream>>>(wih, wihb, 393216);
    // softmax over i -> bf16 Msb
    softmax_dim1<<<dim3(2, 32), blk, 0, stream>>>(Mf, Msb);
    // ctx[b] = Ms[b] @ x2[b]  (NT with x2tb = x2^T per batch) bf16 out
    gemm_bf16<<<dim3(2, 4, 32), blk, 0, stream>>>(
        Msb, 512, 262144, x2tb, 512, 131072, ctxb, 256, 131072, 512,
        nullptr, nullptr, 0, 0, 0, 1);
    // xp = x1 @ wih[:, :256]^T + bih   fp32 out
    gemm_bf16<<<dim3(6, 128, 1), blk, 0, stream>>>(
        x1b, 256, 0, wihb, 512, 0, xp, 768, 0, 256,
        bih, nullptr, 0, 0, 0, 0);
    // xp += ctx @ wih[:, 256:]^T
    gemm_bf16<<<dim3(6, 128, 1), blk, 0, stream>>>(
        ctxb, 256, 0, wihb + 256, 512, 0, xp, 768, 0, 256,
        nullptr, nullptr, 0, 0, 1, 0);
    // GRU recurrence
    gru_kernel<<<dim3(32), dim3(768), 0, stream>>>(xp, whh, bhh, out);
}

// Round 6
// 1109.225 us; speedup vs baseline: 1.4109x; 1.0008x over previous
//
#include <hip/hip_runtime.h>
#include <hip/hip_bf16.h>
#include <cstdint>
#include <cstddef>

// ---------------------------------------------------------------------------
// EnrichAttention: B=32, L1=L2=512, H=A=256, 3H=768, 2H=512
// R6: GRU scratch weight loads widened 4B -> 16B (H2x4 w[32], dwordx4).
//     GEMM/MFMA pipeline identical to the passing R5.
// ---------------------------------------------------------------------------

typedef _Float16 h2 __attribute__((ext_vector_type(2)));
typedef short s8v __attribute__((ext_vector_type(8)));    // 8 bf16 (4 VGPRs)
typedef float f4v __attribute__((ext_vector_type(4)));    // MFMA accumulator
struct alignas(16) H2x4 { h2 a, b, c, d; };

#if __has_builtin(__builtin_amdgcn_fdot2)
#define FDOT2(a, b, c) __builtin_amdgcn_fdot2((a), (b), (c), false)
#else
#define FDOT2(a, b, c) ((c) + (float)(a)[0] * (float)(b)[0] + (float)(a)[1] * (float)(b)[1])
#endif

#if __has_builtin(__builtin_amdgcn_sched_barrier)
#define SCHED_FENCE() __builtin_amdgcn_sched_barrier(0)
#else
#define SCHED_FENCE() asm volatile("" ::: "memory")
#endif

// Workgroup barrier waiting only on LDS (lgkmcnt). Only hh/hp (LDS) carry
// cross-thread deps in the GRU loop. (Validated in R2/R5.)
__device__ __forceinline__ void bar_lds() {
    asm volatile("s_waitcnt lgkmcnt(0)\n\ts_barrier" ::: "memory");
}

__device__ __forceinline__ float fast_exp(float x) {
#if __has_builtin(__builtin_amdgcn_exp2f)
    return __builtin_amdgcn_exp2f(x * 1.44269504f);
#else
    return __expf(x);
#endif
}
__device__ __forceinline__ float fast_rcp(float x) {
#if __has_builtin(__builtin_amdgcn_rcpf)
    return __builtin_amdgcn_rcpf(x);
#else
    return 1.f / x;
#endif
}
__device__ __forceinline__ float fast_sig(float x) { return fast_rcp(1.f + fast_exp(-x)); }
__device__ __forceinline__ float fast_tanh(float x) {
    return 1.f - 2.f * fast_rcp(1.f + fast_exp(2.f * x));
}

// ---------------------------------------------------------------------------
// MFMA bf16 NT GEMM: C[M,N] = A[M,K] * B[N,K]^T, A/B bf16, C fp32 or bf16.
// 128x128 block, 4 waves (2x2 of 64x64), BK=32. (Verified in R5.)
// ---------------------------------------------------------------------------
__global__ __launch_bounds__(256) void gemm_bf16(
    const __hip_bfloat16* __restrict__ A, int lda, long long sA,
    const __hip_bfloat16* __restrict__ B, int ldb, long long sB,
    void* __restrict__ C, int ldc, long long sC,
    int K,
    const float* __restrict__ bias,
    const float* __restrict__ emul, int ldmul,
    int relu, int accum, int out_bf16)
{
    __shared__ short As[128][40];
    __shared__ short Bs[128][40];

    const int tid  = threadIdx.x;
    const int wave = tid >> 6, lane = tid & 63;
    const int quad = lane >> 4, l16 = lane & 15;
    const int wrow = (wave >> 1) * 64, wcol = (wave & 1) * 64;
    const int m0 = blockIdx.y * 128, n0 = blockIdx.x * 128;

    const short* Ab = (const short*)A + (size_t)blockIdx.z * sA;
    const short* Bb = (const short*)B + (size_t)blockIdx.z * sB;

    f4v acc[4][4];
#pragma unroll
    for (int i = 0; i < 4; ++i)
#pragma unroll
        for (int j = 0; j < 4; ++j) acc[i][j] = 0.f;

    const int r0 = tid >> 2,        s0 = (tid & 3) * 8;
    const int r1 = (tid + 256) >> 2, s1 = ((tid + 256) & 3) * 8;

    for (int k0 = 0; k0 < K; k0 += 32) {
        *(s8v*)&As[r0][s0] = *(const s8v*)(Ab + (size_t)(m0 + r0) * lda + k0 + s0);
        *(s8v*)&As[r1][s1] = *(const s8v*)(Ab + (size_t)(m0 + r1) * lda + k0 + s1);
        *(s8v*)&Bs[r0][s0] = *(const s8v*)(Bb + (size_t)(n0 + r0) * ldb + k0 + s0);
        *(s8v*)&Bs[r1][s1] = *(const s8v*)(Bb + (size_t)(n0 + r1) * ldb + k0 + s1);
        __syncthreads();

        s8v af[4], bf[4];
#pragma unroll
        for (int i = 0; i < 4; ++i)
            af[i] = *(const s8v*)&As[wrow + i * 16 + l16][quad * 8];
#pragma unroll
        for (int j = 0; j < 4; ++j)
            bf[j] = *(const s8v*)&Bs[wcol + j * 16 + l16][quad * 8];
#pragma unroll
        for (int i = 0; i < 4; ++i)
#pragma unroll
            for (int j = 0; j < 4; ++j)
                acc[i][j] = __builtin_amdgcn_mfma_f32_16x16x32_bf16(
                    af[i], bf[j], acc[i][j], 0, 0, 0);
        __syncthreads();
    }

    float* Cf = (float*)C + (size_t)blockIdx.z * sC;
    __hip_bfloat16* Cb = (__hip_bfloat16*)C + (size_t)blockIdx.z * sC;
#pragma unroll
    for (int i = 0; i < 4; ++i)
#pragma unroll
        for (int j = 0; j < 4; ++j)
#pragma unroll
            for (int r = 0; r < 4; ++r) {
                const int m = m0 + wrow + i * 16 + quad * 4 + r;
                const int n = n0 + wcol + j * 16 + l16;
                float v = acc[i][j][r];
                if (bias)  v += bias[n];
                if (accum) v += Cf[(size_t)m * ldc + n];
                if (emul)  v *= emul[(size_t)m * ldmul + n];
                if (relu)  v = fmaxf(v, 0.f);
                if (out_bf16) Cb[(size_t)m * ldc + n] = __float2bfloat16(v);
                else          Cf[(size_t)m * ldc + n] = v;
            }
}

// fp32 -> bf16 elementwise (n % 4 == 0)
__global__ __launch_bounds__(256) void f2b(
    const float* __restrict__ s, __hip_bfloat16* __restrict__ d, int n)
{
    const int i = (blockIdx.x * 256 + threadIdx.x) * 4;
    if (i < n) {
        float4 v = *(const float4*)(s + i);
        d[i + 0] = __float2bfloat16(v.x);
        d[i + 1] = __float2bfloat16(v.y);
        d[i + 2] = __float2bfloat16(v.z);
        d[i + 3] = __float2bfloat16(v.w);
    }
}

// fp32 [Z][R][C] -> bf16 [Z][C][R] tiled transpose
__global__ __launch_bounds__(256) void tr_f2b(
    const float* __restrict__ src, __hip_bfloat16* __restrict__ dst,
    int R, int C, long long sS, long long sD)
{
    __shared__ float t[32][33];
    const int r0 = blockIdx.y * 32, c0 = blockIdx.x * 32;
    const int tx = threadIdx.x & 31, ty = threadIdx.x >> 5;
    const float* S = src + (size_t)blockIdx.z * sS;
    __hip_bfloat16* Dd = dst + (size_t)blockIdx.z * sD;
#pragma unroll
    for (int i = 0; i < 32; i += 8)
        t[ty + i][tx] = S[(size_t)(r0 + ty + i) * C + c0 + tx];
    __syncthreads();
#pragma unroll
    for (int i = 0; i < 32; i += 8)
        Dd[(size_t)(c0 + ty + i) * R + r0 + tx] = __float2bfloat16(t[tx][ty + i]);
}

// softmax over axis=1 (i) for each (b, j): fp32 in, bf16 out
__global__ __launch_bounds__(256) void softmax_dim1(
    const float* __restrict__ Mf, __hip_bfloat16* __restrict__ Ms)
{
    const int j = blockIdx.x * 256 + threadIdx.x;
    const float* base = Mf + (size_t)blockIdx.y * 262144;
    __hip_bfloat16* ob = Ms + (size_t)blockIdx.y * 262144;

    float mx = -1e30f;
    for (int i = 0; i < 512; ++i)
        mx = fmaxf(mx, base[(size_t)i * 512 + j]);
    float s = 0.f;
    for (int i = 0; i < 512; ++i)
        s += __expf(base[(size_t)i * 512 + j] - mx);
    const float inv = 1.f / s;
    for (int i = 0; i < 512; ++i)
        ob[(size_t)i * 512 + j] =
            __float2bfloat16(__expf(base[(size_t)i * 512 + j] - mx) * inv);
}

// ---------------------------------------------------------------------------
// GRU: R2 structure, but w stored as H2x4 w[32] -> 16-B scratch loads
// (buffer_load_dwordx4), 4x fewer memory instructions per step.
// w[k] = cols {8k..8k+7} of whh row o; hv[k] = h{8k..8k+7}. Same mapping.
// ---------------------------------------------------------------------------
__global__
__attribute__((amdgpu_flat_work_group_size(768, 768)))
__attribute__((amdgpu_waves_per_eu(3, 3)))
void gru_kernel(
    const float* __restrict__ xproj,   // [B, T, 768]
    const float* __restrict__ whh,     // [768, 256]
    const float* __restrict__ bhh,     // [768]
    float* __restrict__ out)           // [B, T, 256]
{
    const int b = blockIdx.x;
    const int o = threadIdx.x;

    __shared__ __align__(16) h2 hh[128];
    __shared__ float hp[768];

    H2x4 w[32];
    {
        const float4* wr = (const float4*)(whh + (size_t)o * 256);
#pragma unroll
        for (int k = 0; k < 32; ++k) {
            float4 t0 = wr[2 * k + 0];   // cols 8k..8k+3
            float4 t1 = wr[2 * k + 1];   // cols 8k+4..8k+7
            H2x4 c;
            c.a[0] = (_Float16)t0.x; c.a[1] = (_Float16)t0.y;
            c.b[0] = (_Float16)t0.z; c.b[1] = (_Float16)t0.w;
            c.c[0] = (_Float16)t1.x; c.c[1] = (_Float16)t1.y;
            c.d[0] = (_Float16)t1.z; c.d[1] = (_Float16)t1.w;
            w[k] = c;
            if ((k & 3) == 3) SCHED_FENCE();
        }
    }
    const float bias_o = bhh[o];
    const float* xb_base = xproj + (size_t)b * 512 * 768;

    float hA = 0.f, hB = 0.f;
    float2 xr, xz, xn;
    if (o < 128) {
        h2 z; z[0] = (_Float16)0.f; z[1] = (_Float16)0.f;
        hh[o] = z;
        const float2* r0 = (const float2*)xb_base;
        xr = r0[o]; xz = r0[128 + o]; xn = r0[256 + o];
    }
    bar_lds();

    for (int t = 0; t < 512; ++t) {
        float a0 = bias_o, a1 = 0.f, a2 = 0.f, a3 = 0.f;
        const H2x4* hv = (const H2x4*)hh;
#pragma unroll
        for (int k = 0; k < 32; ++k) {
            H2x4 wk = w[k];
            H2x4 v  = hv[k];
            a0 = FDOT2(wk.a, v.a, a0);
            a1 = FDOT2(wk.b, v.b, a1);
            a2 = FDOT2(wk.c, v.c, a2);
            a3 = FDOT2(wk.d, v.d, a3);
        }
        hp[o] = (a0 + a1) + (a2 + a3);
        bar_lds();

        if (o < 128) {
            const int tn = (t + 1) & 511;
            const float2* rn = (const float2*)(xb_base + (size_t)tn * 768);
            float2 nr = rn[o], nz = rn[128 + o], nn = rn[256 + o];

            float2 hr = *(const float2*)&hp[2 * o];
            float2 hz = *(const float2*)&hp[256 + 2 * o];
            float2 hn = *(const float2*)&hp[512 + 2 * o];

            float r0 = fast_sig(xr.x + hr.x), r1 = fast_sig(xr.y + hr.y);
            float z0 = fast_sig(xz.x + hz.x), z1 = fast_sig(xz.y + hz.y);
            float n0 = fast_tanh(xn.x + r0 * hn.x), n1 = fast_tanh(xn.y + r1 * hn.y);
            float nh0 = (1.f - z0) * n0 + z0 * hA;
            float nh1 = (1.f - z1) * n1 + z1 * hB;
            hA = nh0; hB = nh1;

            h2 p; p[0] = (_Float16)nh0; p[1] = (_Float16)nh1;
            hh[o] = p;
            ((float2*)(out + ((size_t)b * 512 + t) * 256))[o] = make_float2(nh0, nh1);

            xr = nr; xz = nz; xn = nn;
        }
        bar_lds();
    }
}

extern "C" void kernel_launch(void* const* d_in, const int* in_sizes, int n_in,
                              void* d_out, int out_size, void* d_ws, size_t ws_size,
                              hipStream_t stream)
{
    (void)in_sizes; (void)n_in; (void)out_size; (void)ws_size;

    const float* x1  = (const float*)d_in[0];   // [32,512,256]
    const float* x2  = (const float*)d_in[1];   // [32,512,256]
    const float* w1  = (const float*)d_in[2];   // [256,256]
    const float* w2  = (const float*)d_in[3];   // [256,256]
    const float* Dm  = (const float*)d_in[4];   // [256,256]
    const float* Wm  = (const float*)d_in[5];   // [512,512]
    const float* wih = (const float*)d_in[6];   // [768,512]
    const float* whh = (const float*)d_in[7];   // [768,256]
    const float* bih = (const float*)d_in[8];   // [768]
    const float* bhh = (const float*)d_in[9];   // [768]
    float* out = (float*)d_out;

    // Workspace aliasing identical to the passing R5.
    char* base = (char*)d_ws;
    __hip_bfloat16* w1b  = (__hip_bfloat16*)(base + 0);
    __hip_bfloat16* w2b  = (__hip_bfloat16*)(base + 131072);
    __hip_bfloat16* Dtb  = (__hip_bfloat16*)(base + 262144);
    float*          Mf   = (float*)(base + 0);
    float*          xp   = (float*)(base + 0);
    __hip_bfloat16* a1b  = (__hip_bfloat16*)(base + 33554432);
    __hip_bfloat16* a1db = (__hip_bfloat16*)(base + 41943040);
    __hip_bfloat16* Msb  = (__hip_bfloat16*)(base + 33554432);
    __hip_bfloat16* x1b  = (__hip_bfloat16*)(base + 50331648);
    __hip_bfloat16* x2b  = (__hip_bfloat16*)(base + 58720256);
    __hip_bfloat16* ctxb = (__hip_bfloat16*)(base + 58720256);
    __hip_bfloat16* x2tb = (__hip_bfloat16*)(base + 67108864);
    __hip_bfloat16* a2b  = (__hip_bfloat16*)(base + 75497472);
    __hip_bfloat16* wihb = (__hip_bfloat16*)(base + 75497472);

    dim3 blk(256);

    f2b<<<dim3(4096), blk, 0, stream>>>(x1, x1b, 4194304);
    f2b<<<dim3(4096), blk, 0, stream>>>(x2, x2b, 4194304);
    f2b<<<dim3(64),   blk, 0, stream>>>(w1, w1b, 65536);
    f2b<<<dim3(64),   blk, 0, stream>>>(w2, w2b, 65536);
    tr_f2b<<<dim3(8, 16, 32), blk, 0, stream>>>(x2, x2tb, 512, 256, 131072, 131072);
    tr_f2b<<<dim3(8, 8, 1),   blk, 0, stream>>>(Dm, Dtb, 256, 256, 0, 0);

    gemm_bf16<<<dim3(2, 128, 1), blk, 0, stream>>>(
        x1b, 256, 0, w1b, 256, 0, a1b, 256, 0, 256,
        nullptr, nullptr, 0, 1, 0, 1);
    gemm_bf16<<<dim3(2, 128, 1), blk, 0, stream>>>(
        x2b, 256, 0, w2b, 256, 0, a2b, 256, 0, 256,
        nullptr, nullptr, 0, 1, 0, 1);
    gemm_bf16<<<dim3(2, 128, 1), blk, 0, stream>>>(
        a1b, 256, 0, Dtb, 256, 0, a1db, 256, 0, 256,
        nullptr, nullptr, 0, 0, 0, 1);
    gemm_bf16<<<dim3(4, 4, 32), blk, 0, stream>>>(
        a1db, 256, 131072, a2b, 256, 131072, Mf, 512, 262144, 256,
        nullptr, Wm, 512, 0, 0, 0);
    f2b<<<dim3(384), blk, 0, stream>>>(wih, wihb, 393216);
    softmax_dim1<<<dim3(2, 32), blk, 0, stream>>>(Mf, Msb);
    gemm_bf16<<<dim3(2, 4, 32), blk, 0, stream>>>(
        Msb, 512, 262144, x2tb, 512, 131072, ctxb, 256, 131072, 512,
        nullptr, nullptr, 0, 0, 0, 1);
    gemm_bf16<<<dim3(6, 128, 1), blk, 0, stream>>>(
        x1b, 256, 0, wihb, 512, 0, xp, 768, 0, 256,
        bih, nullptr, 0, 0, 0, 0);
    gemm_bf16<<<dim3(6, 128, 1), blk, 0, stream>>>(
        ctxb, 256, 0, wihb + 256, 512, 0, xp, 768, 0, 256,
        nullptr, nullptr, 0, 0, 1, 0);
    gru_kernel<<<dim3(32), dim3(768), 0, stream>>>(xp, whh, bhh, out);
}